// Round 3
// baseline (3734.372 us; speedup 1.0000x reference)
//
#include <hip/hip_runtime.h>
#include <hip/hip_bf16.h>

#define N_NODES 100000
#define N_EDGES 3200000
#define IN_DIM 20
#define HID 64

// ---------------- K0: detect edge_index dtype (int32 vs int64) ----------------
// int64 values < 2^31 have all-zero high words at odd 32-bit indices.
__global__ void k_detect(const unsigned* __restrict__ e, int* __restrict__ flag)
{
    int lane = threadIdx.x; // 64 threads
    unsigned hi = e[2 * lane + 1];
    unsigned long long ballot = __ballot(hi != 0u);
    if (lane == 0) *flag = (ballot == 0ULL) ? 1 : 0; // 1 => int64
}

__device__ __forceinline__ void load_edge(const void* eidx, int i64, int e, int E,
                                          int& s, int& d)
{
    if (i64) {
        const long long* p = (const long long*)eidx;
        s = (int)p[e];
        d = (int)p[(long)E + e];
    } else {
        const int* p = (const int*)eidx;
        s = p[e];
        d = p[(long)E + e];
    }
}

// ---------------- K1: per-edge degree count + 20-dim feature aggregation ----------------
__global__ __launch_bounds__(256) void k_edge_agg(
    const void* __restrict__ eidx, const int* __restrict__ flag,
    const float* __restrict__ x, float* __restrict__ deg,
    float* __restrict__ agg1, int E, int N)
{
    const int i64 = *flag;
    int stride = gridDim.x * blockDim.x;
    for (int e = blockIdx.x * blockDim.x + threadIdx.x; e < E; e += stride) {
        int s, d;
        load_edge(eidx, i64, e, E, s, d);
        if ((unsigned)s >= (unsigned)N || (unsigned)d >= (unsigned)N) continue;
        atomicAdd(&deg[d], 1.0f);
        const float* xs = x + (long)s * IN_DIM;
        float* ad = agg1 + (long)d * IN_DIM;
        #pragma unroll
        for (int k = 0; k < IN_DIM; ++k) atomicAdd(&ad[k], xs[k]);
    }
}

// ---------------- K2: deg -> deg_inv (in place) ----------------
__global__ __launch_bounds__(256) void k_deg_inv(float* __restrict__ deg, int N)
{
    int n = blockIdx.x * blockDim.x + threadIdx.x;
    if (n < N) {
        float dg = deg[n];
        deg[n] = dg > 0.0f ? 1.0f / dg : 0.0f;
    }
}

// ---------------- K3: w[src] += deg_inv[dst] ----------------
__global__ __launch_bounds__(256) void k_edge_w(
    const void* __restrict__ eidx, const int* __restrict__ flag,
    const float* __restrict__ deginv, float* __restrict__ w, int E, int N)
{
    const int i64 = *flag;
    int stride = gridDim.x * blockDim.x;
    for (int e = blockIdx.x * blockDim.x + threadIdx.x; e < E; e += stride) {
        int s, d;
        load_edge(eidx, i64, e, E, s, d);
        if ((unsigned)s >= (unsigned)N || (unsigned)d >= (unsigned)N) continue;
        atomicAdd(&w[s], deginv[d]);
    }
}

// ---------------- K4: per-node layer-1 + fused S1/S2 reductions ----------------
// lane j (0..63) owns output channel j; operands broadcast via __shfl.
__global__ __launch_bounds__(256) void k_node_layer1(
    const float* __restrict__ x, const float* __restrict__ agg1,
    const float* __restrict__ deginv, const float* __restrict__ w,
    const float* __restrict__ W1l, const float* __restrict__ b1,
    const float* __restrict__ W1r,
    float* __restrict__ S1, float* __restrict__ S2, int N)
{
    __shared__ float sW1l[IN_DIM * HID];
    __shared__ float sW1r[IN_DIM * HID];
    __shared__ float sb1[HID];
    for (int i = threadIdx.x; i < IN_DIM * HID; i += blockDim.x) {
        sW1l[i] = W1l[i];
        sW1r[i] = W1r[i];
    }
    if (threadIdx.x < HID) sb1[threadIdx.x] = b1[threadIdx.x];
    __syncthreads();

    const int lane = threadIdx.x & 63;
    const int wave_id = (blockIdx.x * blockDim.x + threadIdx.x) >> 6;
    const int waves_total = (gridDim.x * blockDim.x) >> 6;

    float s1 = 0.0f, s2 = 0.0f;
    for (int n = wave_id; n < N; n += waves_total) {
        // lanes 0..19 hold agg1[n][k]; lanes 32..51 hold x[n][k]
        float v = 0.0f;
        if (lane < IN_DIM) v = agg1[(long)n * IN_DIM + lane];
        else if (lane >= 32 && lane < 32 + IN_DIM) v = x[(long)n * IN_DIM + (lane - 32)];
        float di = deginv[n];
        float h = sb1[lane];
        #pragma unroll
        for (int k = 0; k < IN_DIM; ++k) {
            float ak = __shfl(v, k) * di;
            float xk = __shfl(v, 32 + k);
            h += ak * sW1l[k * HID + lane];
            h += xk * sW1r[k * HID + lane];
        }
        h = fmaxf(h, 0.0f);
        s2 += h;
        s1 += w[n] * h;
    }
    atomicAdd(&S1[lane], s1);
    atomicAdd(&S2[lane], s2);
}

// ---------------- K5: final tiny matvec + bias + mean ----------------
__global__ void k_final(const float* __restrict__ S1, const float* __restrict__ S2,
                        const float* __restrict__ W2l, const float* __restrict__ b2,
                        const float* __restrict__ W2r, float* __restrict__ out, float invN)
{
    int j = threadIdx.x; // 64 threads
    float acc1 = 0.0f, acc2 = 0.0f;
    for (int k = 0; k < HID; ++k) {
        acc1 += S1[k] * W2l[k * HID + j];
        acc2 += S2[k] * W2r[k * HID + j];
    }
    out[j] = acc1 * invN + b2[j] + acc2 * invN;
}

extern "C" void kernel_launch(void* const* d_in, const int* in_sizes, int n_in,
                              void* d_out, int out_size, void* d_ws, size_t ws_size,
                              hipStream_t stream)
{
    const float* x   = (const float*)d_in[0];
    const void* eidx = (const void*)d_in[1];   // [2, E]; dtype detected on device
    const float* W1l = (const float*)d_in[2];
    const float* b1  = (const float*)d_in[3];
    const float* W1r = (const float*)d_in[4];
    const float* W2l = (const float*)d_in[5];
    const float* b2  = (const float*)d_in[6];
    const float* W2r = (const float*)d_in[7];
    float* out = (float*)d_out;

    const int N = N_NODES;
    const int E = N_EDGES;

    // ws layout (floats): deg/deg_inv [N] | w [N] | agg1 [20N] | S1 [64] | S2 [64] | flag [1]
    float* wsf  = (float*)d_ws;
    float* deg  = wsf;
    float* wvec = wsf + N;
    float* agg1 = wsf + 2 * (long)N;
    float* S1   = wsf + 22 * (long)N;
    float* S2   = wsf + 22 * (long)N + HID;
    int*   flag = (int*)(wsf + 22 * (long)N + 2 * HID);

    size_t zero_bytes = (size_t)(22 * (long)N + 2 * HID + 1) * sizeof(float);
    hipMemsetAsync(d_ws, 0, zero_bytes, stream);

    k_detect<<<1, 64, 0, stream>>>((const unsigned*)eidx, flag);
    k_edge_agg<<<2560, 256, 0, stream>>>(eidx, flag, x, deg, agg1, E, N);
    k_deg_inv<<<(N + 255) / 256, 256, 0, stream>>>(deg, N);
    k_edge_w<<<2560, 256, 0, stream>>>(eidx, flag, deg, wvec, E, N);
    k_node_layer1<<<256, 256, 0, stream>>>(x, agg1, deg, wvec, W1l, b1, W1r, S1, S2, N);
    k_final<<<1, HID, 0, stream>>>(S1, S2, W2l, b2, W2r, out, 1.0f / (float)N);
}

// Round 5
// 827.518 us; speedup vs baseline: 4.5127x; 4.5127x over previous
//
#include <hip/hip_runtime.h>
#include <hip/hip_bf16.h>

#define N_NODES 100000
#define N_EDGES 3200000
#define IN_DIM 20
#define HID 64
#define SCAN_CHUNK 1024

// ---------------- K0: detect edge_index dtype (int32 vs int64) ----------------
__global__ void k_detect(const unsigned* __restrict__ e, int* __restrict__ flag)
{
    int lane = threadIdx.x; // 64 threads
    unsigned hi = e[2 * lane + 1];
    unsigned long long ballot = __ballot(hi != 0u);
    if (lane == 0) *flag = (ballot == 0ULL) ? 1 : 0; // 1 => int64
}

__device__ __forceinline__ void load_edge(const void* eidx, int i64, int e, int E,
                                          int& s, int& d)
{
    if (i64) {
        const long long* p = (const long long*)eidx;
        s = (int)p[e];
        d = (int)p[(long)E + e];
    } else {
        const int* p = (const int*)eidx;
        s = p[e];
        d = p[(long)E + e];
    }
}

// ---------------- K_hist: cnt[dst]++ ----------------
__global__ __launch_bounds__(256) void k_hist(
    const void* __restrict__ eidx, const int* __restrict__ flag,
    int* __restrict__ cnt, int E, int N)
{
    const int i64 = *flag;
    int stride = gridDim.x * blockDim.x;
    for (int e = blockIdx.x * blockDim.x + threadIdx.x; e < E; e += stride) {
        int d;
        if (i64) d = (int)((const long long*)eidx)[(long)E + e];
        else     d = ((const int*)eidx)[(long)E + e];
        if ((unsigned)d < (unsigned)N) atomicAdd(&cnt[d], 1);
    }
}

// ---------------- scan: blockwise Hillis-Steele ----------------
__global__ __launch_bounds__(SCAN_CHUNK) void k_scan_block(
    const int* __restrict__ cnt, int* __restrict__ offs, int* __restrict__ bsum, int N)
{
    __shared__ int buf[2][SCAN_CHUNK];
    int t = threadIdx.x;
    int gid = blockIdx.x * SCAN_CHUNK + t;
    int v = (gid < N) ? cnt[gid] : 0;
    int cur = 0;
    buf[0][t] = v;
    __syncthreads();
    for (int off = 1; off < SCAN_CHUNK; off <<= 1) {
        int nv = buf[cur][t] + ((t >= off) ? buf[cur][t - off] : 0);
        buf[cur ^ 1][t] = nv;
        cur ^= 1;
        __syncthreads();
    }
    int inc = buf[cur][t];
    if (gid < N) offs[gid] = inc - v; // exclusive within chunk
    if (t == SCAN_CHUNK - 1) bsum[blockIdx.x] = inc;
}

__global__ void k_scan_partials(int* __restrict__ bsum, int nb)
{
    if (threadIdx.x == 0) {
        int run = 0;
        for (int b = 0; b < nb; ++b) { int v = bsum[b]; bsum[b] = run; run += v; }
    }
}

__global__ __launch_bounds__(256) void k_scan_add(
    int* __restrict__ offs, int* __restrict__ cursor, float* __restrict__ deginv,
    const int* __restrict__ cnt, const int* __restrict__ bsum, int N)
{
    int i = blockIdx.x * blockDim.x + threadIdx.x;
    if (i < N) {
        int o = offs[i] + bsum[i >> 10];
        offs[i] = o;
        cursor[i] = o;
        int c = cnt[i];
        deginv[i] = (c > 0) ? 1.0f / (float)c : 0.0f;
    }
}

// ---------------- K_scatter: build CSR + fused w accumulation ----------------
__global__ __launch_bounds__(256) void k_scatter(
    const void* __restrict__ eidx, const int* __restrict__ flag,
    int* __restrict__ cursor, int* __restrict__ csr,
    const float* __restrict__ deginv, float* __restrict__ w, int E, int N)
{
    const int i64 = *flag;
    int stride = gridDim.x * blockDim.x;
    for (int e = blockIdx.x * blockDim.x + threadIdx.x; e < E; e += stride) {
        int s, d;
        load_edge(eidx, i64, e, E, s, d);
        if ((unsigned)s >= (unsigned)N || (unsigned)d >= (unsigned)N) continue;
        int pos = atomicAdd(&cursor[d], 1);
        csr[pos] = s;
        atomicAdd(&w[s], deginv[d]);
    }
}

// ---------------- K_agg: wave-per-node gather aggregation (no atomics) ----------------
// lanes: group g = lane/20 (3 groups), dim = lane%20; lanes 60..63 idle.
__global__ __launch_bounds__(256) void k_agg(
    const int* __restrict__ offs, const int* __restrict__ cnt,
    const int* __restrict__ csr, const float* __restrict__ x,
    float* __restrict__ agg1, int N)
{
    const int lane = threadIdx.x & 63;
    const int wid = (blockIdx.x * blockDim.x + threadIdx.x) >> 6;
    const int wtot = (gridDim.x * blockDim.x) >> 6;
    const int g = lane / 20;
    const int dim = lane % 20;
    const bool active = lane < 60;

    for (int n = wid; n < N; n += wtot) {
        int base = offs[n];
        int c = cnt[n];
        float v = 0.0f;
        if (active) {
            for (int i = g; i < c; i += 3) {
                int s = csr[base + i];          // broadcast within 20-lane group
                v += x[(long)s * IN_DIM + dim]; // 80B coalesced per group
            }
        }
        float v1 = __shfl(v, lane + 20);
        float v2 = __shfl(v, lane + 40);
        if (lane < 20) agg1[(long)n * IN_DIM + lane] = v + v1 + v2;
    }
}

// ---------------- K4: per-node layer-1 + fused S1/S2 reductions ----------------
__global__ __launch_bounds__(256) void k_node_layer1(
    const float* __restrict__ x, const float* __restrict__ agg1,
    const float* __restrict__ deginv, const float* __restrict__ w,
    const float* __restrict__ W1l, const float* __restrict__ b1,
    const float* __restrict__ W1r,
    float* __restrict__ S1, float* __restrict__ S2, int N)
{
    __shared__ float sW1l[IN_DIM * HID];
    __shared__ float sW1r[IN_DIM * HID];
    __shared__ float sb1[HID];
    for (int i = threadIdx.x; i < IN_DIM * HID; i += blockDim.x) {
        sW1l[i] = W1l[i];
        sW1r[i] = W1r[i];
    }
    if (threadIdx.x < HID) sb1[threadIdx.x] = b1[threadIdx.x];
    __syncthreads();

    const int lane = threadIdx.x & 63;
    const int wave_id = (blockIdx.x * blockDim.x + threadIdx.x) >> 6;
    const int waves_total = (gridDim.x * blockDim.x) >> 6;

    float s1 = 0.0f, s2 = 0.0f;
    for (int n = wave_id; n < N; n += waves_total) {
        float v = 0.0f;
        if (lane < IN_DIM) v = agg1[(long)n * IN_DIM + lane];
        else if (lane >= 32 && lane < 32 + IN_DIM) v = x[(long)n * IN_DIM + (lane - 32)];
        float di = deginv[n];
        float h = sb1[lane];
        #pragma unroll
        for (int k = 0; k < IN_DIM; ++k) {
            float ak = __shfl(v, k) * di;
            float xk = __shfl(v, 32 + k);
            h += ak * sW1l[k * HID + lane];
            h += xk * sW1r[k * HID + lane];
        }
        h = fmaxf(h, 0.0f);
        s2 += h;
        s1 += w[n] * h;
    }
    atomicAdd(&S1[lane], s1);
    atomicAdd(&S2[lane], s2);
}

// ---------------- K5: final tiny matvec + bias + mean ----------------
__global__ void k_final(const float* __restrict__ S1, const float* __restrict__ S2,
                        const float* __restrict__ W2l, const float* __restrict__ b2,
                        const float* __restrict__ W2r, float* __restrict__ out, float invN)
{
    int j = threadIdx.x; // 64 threads
    float acc1 = 0.0f, acc2 = 0.0f;
    for (int k = 0; k < HID; ++k) {
        acc1 += S1[k] * W2l[k * HID + j];
        acc2 += S2[k] * W2r[k * HID + j];
    }
    out[j] = acc1 * invN + b2[j] + acc2 * invN;
}

// ---------------- fallback: old fully-atomic aggregation ----------------
__global__ __launch_bounds__(256) void k_edge_agg_atomic(
    const void* __restrict__ eidx, const int* __restrict__ flag,
    const float* __restrict__ x, float* __restrict__ agg1, int E, int N)
{
    const int i64 = *flag;
    int stride = gridDim.x * blockDim.x;
    for (int e = blockIdx.x * blockDim.x + threadIdx.x; e < E; e += stride) {
        int s, d;
        load_edge(eidx, i64, e, E, s, d);
        if ((unsigned)s >= (unsigned)N || (unsigned)d >= (unsigned)N) continue;
        const float* xs = x + (long)s * IN_DIM;
        float* ad = agg1 + (long)d * IN_DIM;
        #pragma unroll
        for (int k = 0; k < IN_DIM; ++k) atomicAdd(&ad[k], xs[k]);
    }
}

__global__ __launch_bounds__(256) void k_edge_w(
    const void* __restrict__ eidx, const int* __restrict__ flag,
    const float* __restrict__ deginv, float* __restrict__ w, int E, int N)
{
    const int i64 = *flag;
    int stride = gridDim.x * blockDim.x;
    for (int e = blockIdx.x * blockDim.x + threadIdx.x; e < E; e += stride) {
        int s, d;
        load_edge(eidx, i64, e, E, s, d);
        if ((unsigned)s >= (unsigned)N || (unsigned)d >= (unsigned)N) continue;
        atomicAdd(&w[s], deginv[d]);
    }
}

__global__ __launch_bounds__(256) void k_deginv_from_cnt(
    const int* __restrict__ cnt, float* __restrict__ deginv, int N)
{
    int i = blockIdx.x * blockDim.x + threadIdx.x;
    if (i < N) {
        int c = cnt[i];
        deginv[i] = (c > 0) ? 1.0f / (float)c : 0.0f;
    }
}

extern "C" void kernel_launch(void* const* d_in, const int* in_sizes, int n_in,
                              void* d_out, int out_size, void* d_ws, size_t ws_size,
                              hipStream_t stream)
{
    const float* x   = (const float*)d_in[0];
    const void* eidx = (const void*)d_in[1];
    const float* W1l = (const float*)d_in[2];
    const float* b1  = (const float*)d_in[3];
    const float* W1r = (const float*)d_in[4];
    const float* W2l = (const float*)d_in[5];
    const float* b2  = (const float*)d_in[6];
    const float* W2r = (const float*)d_in[7];
    float* out = (float*)d_out;

    const int N = N_NODES;
    const int E = N_EDGES;
    const long NL = N;

    // CSR-path layout (4B words):
    // cnt[N] | w[N] | deginv[N] | offs[N] | cursor[N] | csr[E] | agg1[20N] | S1[64] S2[64] flag[1] bsum[128]
    const size_t words_needed = 25 * (size_t)N + (size_t)E + 64 + 64 + 1 + 128;

    int*   cnt    = (int*)d_ws;
    float* wvec   = (float*)d_ws + NL;
    float* deginv = (float*)d_ws + 2 * NL;
    int*   offs   = (int*)d_ws + 3 * NL;
    int*   cursor = (int*)d_ws + 4 * NL;
    int*   csr    = (int*)d_ws + 5 * NL;
    float* agg1   = (float*)d_ws + 5 * NL + E;
    float* S1     = (float*)d_ws + 25 * NL + E;
    float* S2     = S1 + HID;
    int*   flag   = (int*)(S2 + HID);
    int*   bsum   = flag + 1;

    if (ws_size >= words_needed * 4) {
        // zero: cnt + w (adjacent), and S1/S2/flag tail
        hipMemsetAsync(d_ws, 0, 2 * (size_t)N * sizeof(int), stream);
        hipMemsetAsync(S1, 0, (2 * HID + 1) * sizeof(float), stream);

        k_detect<<<1, 64, 0, stream>>>((const unsigned*)eidx, flag);
        k_hist<<<2048, 256, 0, stream>>>(eidx, flag, cnt, E, N);

        int nb = (N + SCAN_CHUNK - 1) / SCAN_CHUNK; // 98
        k_scan_block<<<nb, SCAN_CHUNK, 0, stream>>>(cnt, offs, bsum, N);
        k_scan_partials<<<1, 64, 0, stream>>>(bsum, nb);
        k_scan_add<<<(N + 255) / 256, 256, 0, stream>>>(offs, cursor, deginv, cnt, bsum, N);

        k_scatter<<<2048, 256, 0, stream>>>(eidx, flag, cursor, csr, deginv, wvec, E, N);
        k_agg<<<1024, 256, 0, stream>>>(offs, cnt, csr, x, agg1, N);
        k_node_layer1<<<256, 256, 0, stream>>>(x, agg1, deginv, wvec, W1l, b1, W1r, S1, S2, N);
        k_final<<<1, HID, 0, stream>>>(S1, S2, W2l, b2, W2r, out, 1.0f / (float)N);
    } else {
        // fallback: atomic path (layout: cnt[N] | w[N] | deginv[N] | agg1[20N] | S1 S2 flag)
        float* agg1f = (float*)d_ws + 3 * NL;
        float* S1f   = (float*)d_ws + 23 * NL;
        float* S2f   = S1f + HID;
        int*   flagf = (int*)(S2f + HID);

        hipMemsetAsync(d_ws, 0, (23 * (size_t)N + 2 * HID + 1) * sizeof(float), stream);
        k_detect<<<1, 64, 0, stream>>>((const unsigned*)eidx, flagf);
        k_hist<<<2048, 256, 0, stream>>>(eidx, flagf, cnt, E, N);
        k_deginv_from_cnt<<<(N + 255) / 256, 256, 0, stream>>>(cnt, deginv, N);
        k_edge_agg_atomic<<<2048, 256, 0, stream>>>(eidx, flagf, x, agg1f, E, N);
        k_edge_w<<<2048, 256, 0, stream>>>(eidx, flagf, deginv, wvec, E, N);
        k_node_layer1<<<256, 256, 0, stream>>>(x, agg1f, deginv, wvec, W1l, b1, W1r, S1f, S2f, N);
        k_final<<<1, HID, 0, stream>>>(S1f, S2f, W2l, b2, W2r, out, 1.0f / (float)N);
    }
}